// Round 7
// baseline (317.131 us; speedup 1.0000x reference)
//
#include <hip/hip_runtime.h>
#include <stdint.h>

#define NTOK   8192
#define DIM    1024
#define NEXP   8
#define MAXP   8192

#define BM 128
#define BN 128

typedef float  f32x4  __attribute__((ext_vector_type(4)));
typedef __bf16 bf16x8 __attribute__((ext_vector_type(8)));

__device__ __forceinline__ unsigned short f32_to_bf16(float f) {
  union { float f; unsigned int u; } v; v.f = f;
  unsigned int u = v.u;
  unsigned int r = (u + 0x7FFFu + ((u >> 16) & 1u)) >> 16;
  return (unsigned short)r;
}

// ---------------------------------------------------------------------------
// Fused prep.
// Blocks [0,2048): We fp32 [e][d][h] -> Wf bf16 fragment-major:
//   elem(( nj*32 + s )*64 + lane)*8 + el  where n = nj*16 + (lane&15),
//   k = s*32 + (lane>>4)*8 + el.  Wave writes one contiguous 1KB per (nj,s).
// Blocks [2048,4096): fp64 gate scores + x->bf16.
// ---------------------------------------------------------------------------
__global__ __launch_bounds__(256) void prep_kernel(
    const float* __restrict__ We, unsigned short* __restrict__ Wf,
    const float* __restrict__ x, const float* __restrict__ Wg,
    const float* __restrict__ bg, unsigned short* __restrict__ Xbf,
    int* __restrict__ tok_ee, float2* __restrict__ tok_w) {
  __shared__ float tile[64][65];
  const int bid = blockIdx.x;
  if (bid < 2048) {
    const int e  = bid >> 8;
    const int d0 = ((bid >> 4) & 15) * 64;   // k block
    const int h0 = (bid & 15) * 64;          // n block
    const int t  = threadIdx.x;
    const int tx = t & 63, ty = t >> 6;
    const float* src = We + (size_t)e * DIM * DIM;
#pragma unroll
    for (int i = 0; i < 16; ++i) {
      int d = ty + i * 4;
      tile[d][tx] = src[(size_t)(d0 + d) * DIM + (h0 + tx)];
    }
    __syncthreads();
    const int w = t >> 6, lane = t & 63;
    const int fm = lane & 15, fq = lane >> 4;
#pragma unroll
    for (int p = 0; p < 2; ++p) {
      int idxl = w * 2 + p;                  // 0..7: (njl 0..3, sl 0..1)
      int njl = idxl >> 1, sl = idxl & 1;
      int hl  = njl * 16 + fm;
      unsigned int pk[4];
#pragma unroll
      for (int q = 0; q < 4; ++q) {
        int dl = sl * 32 + fq * 8 + q * 2;
        pk[q] = (unsigned int)f32_to_bf16(tile[dl][hl]) |
                ((unsigned int)f32_to_bf16(tile[dl + 1][hl]) << 16);
      }
      int nj = (h0 >> 4) + njl, s = (d0 >> 5) + sl;
      size_t idx = (((size_t)nj * 32 + s) * 64 + lane) * 8;
      *(uint4*)&Wf[((size_t)e << 20) + idx] = make_uint4(pk[0], pk[1], pk[2], pk[3]);
    }
    return;
  }
  // ---- gate scores ----
  const int blk  = bid - 2048;
  const int wave = threadIdx.x >> 6;
  const int lane = threadIdx.x & 63;
  const int tok  = blk * 4 + wave;

  const float* xr = x + (size_t)tok * DIM + lane * 16;
  float xs[16];
#pragma unroll
  for (int i = 0; i < 4; ++i) *(f32x4*)&xs[i * 4] = *(const f32x4*)(xr + i * 4);

  unsigned int packed[8];
#pragma unroll
  for (int i = 0; i < 8; ++i)
    packed[i] = (unsigned int)f32_to_bf16(xs[2 * i]) |
                ((unsigned int)f32_to_bf16(xs[2 * i + 1]) << 16);
  uint4* xb = (uint4*)(Xbf + (size_t)tok * DIM + lane * 16);
  xb[0] = make_uint4(packed[0], packed[1], packed[2], packed[3]);
  xb[1] = make_uint4(packed[4], packed[5], packed[6], packed[7]);

  double acc[8] = {0, 0, 0, 0, 0, 0, 0, 0};
  const float* wr = Wg + (size_t)(lane * 16) * NEXP;
#pragma unroll
  for (int i = 0; i < 16; ++i) {
    f32x4 wa = *(const f32x4*)(wr + i * 8);
    f32x4 wb = *(const f32x4*)(wr + i * 8 + 4);
    double xd = (double)xs[i];
    acc[0] += xd * (double)wa[0]; acc[1] += xd * (double)wa[1];
    acc[2] += xd * (double)wa[2]; acc[3] += xd * (double)wa[3];
    acc[4] += xd * (double)wb[0]; acc[5] += xd * (double)wb[1];
    acc[6] += xd * (double)wb[2]; acc[7] += xd * (double)wb[3];
  }
#pragma unroll
  for (int m = 1; m < 64; m <<= 1) {
#pragma unroll
    for (int e = 0; e < 8; ++e) acc[e] += __shfl_xor(acc[e], m, 64);
  }

  if (lane == 0) {
    float s[8];
#pragma unroll
    for (int e = 0; e < 8; ++e) s[e] = (float)acc[e] + bg[e];
    int i0 = 0; float v0 = s[0];
#pragma unroll
    for (int e = 1; e < 8; ++e) if (s[e] > v0) { v0 = s[e]; i0 = e; }
    int i1 = -1; float v1 = -3.4e38f;
#pragma unroll
    for (int e = 0; e < 8; ++e) if (e != i0 && s[e] > v1) { v1 = s[e]; i1 = e; }
    float t1 = expf(v1 - v0);
    float den = 1.0f + t1;
    tok_ee[tok] = i0 | (i1 << 8);
    tok_w[tok]  = make_float2(1.0f / den, t1 / den);
  }
}

// ---------------------------------------------------------------------------
// Deterministic compaction. pair_token[slot] = (tok<<1)|which.
// Also writes counts[0..7] and tile_base in counts[8..15] (prefix of
// ceil(cnt/128) -- global tile index base for Af).
// ---------------------------------------------------------------------------
__global__ __launch_bounds__(1024) void compact_kernel(
    const int* __restrict__ tok_ee, const float2* __restrict__ tok_w,
    int* __restrict__ counts, int* __restrict__ pair_token,
    float* __restrict__ pair_w) {
  __shared__ int wave_cnt[16][NEXP];
  __shared__ int wave_off[16][NEXP];
  __shared__ int base[NEXP];
  __shared__ int chunk_tot[NEXP];
  const int tid = threadIdx.x, wave = tid >> 6, lane = tid & 63;
  if (tid < NEXP) base[tid] = 0;
  __syncthreads();
  for (int c = 0; c < NTOK / 1024; ++c) {
    const int t = c * 1024 + tid;
    const int p = tok_ee[t];
    const int e0 = p & 255, e1 = (p >> 8) & 255;
    const float2 w = tok_w[t];
    int pre0 = 0, pre1 = 0;
    const unsigned long long below = (1ull << lane) - 1ull;
#pragma unroll
    for (int e = 0; e < NEXP; ++e) {
      unsigned long long m = __ballot(e0 == e || e1 == e);
      if (e0 == e) pre0 = __popcll(m & below);
      if (e1 == e) pre1 = __popcll(m & below);
      if (lane == 0) wave_cnt[wave][e] = __popcll(m);
    }
    __syncthreads();
    if (tid < NEXP) {
      int s = 0;
      for (int w2 = 0; w2 < 16; ++w2) {
        wave_off[w2][tid] = s;
        s += wave_cnt[w2][tid];
      }
      chunk_tot[tid] = s;
    }
    __syncthreads();
    const int s0 = base[e0] + wave_off[wave][e0] + pre0;
    const int s1 = base[e1] + wave_off[wave][e1] + pre1;
    pair_token[e0 * MAXP + s0] = (t << 1);     pair_w[e0 * MAXP + s0] = w.x;
    pair_token[e1 * MAXP + s1] = (t << 1) | 1; pair_w[e1 * MAXP + s1] = w.y;
    __syncthreads();
    if (tid < NEXP) base[tid] += chunk_tot[tid];
    __syncthreads();
  }
  if (tid < NEXP) counts[tid] = base[tid];
  __syncthreads();
  if (tid == 0) {
    int run = 0;
    for (int e = 0; e < NEXP; ++e) { counts[8 + e] = run; run += (base[e] + 127) >> 7; }
  }
}

// ---------------------------------------------------------------------------
// Regather: Xbf token rows -> Af in MFMA A-fragment-major order per tile:
//   Af[tile*131072 + ((ri*32 + s)*64 + lane)*8 + el] = X[token(m)][k]
//   with m = ri*16 + (lane&15), k = s*32 + (lane>>4)*8 + el.
// Writes: 1KB coalesced per wave per s. Pad rows (>= cnt) written as zeros.
// e = id&7 XCD swizzle so Af[e] is produced in the XCD that consumes it.
// ---------------------------------------------------------------------------
__global__ __launch_bounds__(256) void regather(
    const unsigned short* __restrict__ Xbf, const int* __restrict__ counts,
    const int* __restrict__ pair_token, unsigned short* __restrict__ Af) {
  const int id   = blockIdx.x;
  const int e    = id & 7;
  const int half = (id >> 3) & 1;
  const int mt   = id >> 4;
  const int cnt  = counts[e];
  const int m0   = mt * BM;
  if (m0 >= cnt) return;
  const int tile = counts[8 + e] + mt;

  const int wave = threadIdx.x >> 6;
  const int lane = threadIdx.x & 63;
  const int fm   = lane & 15, fq = lane >> 4;
  const int ri   = half * 4 + wave;

  const int gr = m0 + ri * 16 + fm;
  const int pt = (gr < cnt) ? (pair_token[e * MAXP + gr] >> 1) : -1;
  const unsigned short* src = Xbf + (size_t)(pt < 0 ? 0 : pt) * DIM + fq * 8;
  unsigned short* dst = Af + (size_t)tile * 131072 + ((size_t)ri * 32) * 512 + lane * 8;

#pragma unroll 4
  for (int s = 0; s < 32; ++s) {
    uint4 v = make_uint4(0, 0, 0, 0);
    if (pt >= 0) v = *(const uint4*)(src + s * 32);
    *(uint4*)(dst + s * 512) = v;
  }
}

// ---------------------------------------------------------------------------
// Grouped GEMM — zero LDS, zero barriers. All A/B fragments are contiguous
// 1KB coalesced wave loads from fragment-major Af/Wf; fully unrolled K with
// a 2-deep register pipeline -> compiler emits fine-grained vmcnt (AITER
// style), no vmcnt(0) drains in the loop.
// ---------------------------------------------------------------------------
__global__ __launch_bounds__(256) void moe_gemm(
    const unsigned short* __restrict__ Af, const unsigned short* __restrict__ Wf,
    const float* __restrict__ be, const int* __restrict__ counts,
    const int* __restrict__ pair_token, const float* __restrict__ pair_w,
    float* __restrict__ part, float* __restrict__ Y, int use_part) {
  const int id  = blockIdx.x;
  const int e   = id & 7;
  const int n0  = ((id >> 3) & 7) * BN;
  const int m0  = (id >> 6) * BM;
  const int cnt = counts[e];
  if (m0 >= cnt) return;
  const int tile = counts[8 + e] + (m0 >> 7);

  const int tid  = threadIdx.x;
  const int wave = tid >> 6;
  const int lane = tid & 63;
  const int fm   = lane & 15;
  const int fq   = lane >> 4;
  const int wm   = wave >> 1;
  const int wn   = wave & 1;

  const unsigned short* baseA = Af + (size_t)tile * 131072 + lane * 8;
  const unsigned short* baseB = Wf + ((size_t)e << 20) + lane * 8;
  const int ri0 = wm * 4;                 // A row-groups this wave
  const int nj0 = (n0 >> 4) + wn * 4;     // B col-groups this wave

  f32x4 acc[4][4];
#pragma unroll
  for (int i = 0; i < 4; ++i)
#pragma unroll
    for (int j = 0; j < 4; ++j) { f32x4 z = {0.f, 0.f, 0.f, 0.f}; acc[i][j] = z; }

  bf16x8 a[2][4], b[2][4];
#pragma unroll
  for (int i = 0; i < 4; ++i)
    a[0][i] = *(const bf16x8*)(baseA + (size_t)((ri0 + i) * 32) * 512);
#pragma unroll
  for (int j = 0; j < 4; ++j)
    b[0][j] = *(const bf16x8*)(baseB + (size_t)((nj0 + j) * 32) * 512);

#pragma unroll
  for (int s = 0; s < 32; ++s) {
    const int cur = s & 1, nxt = cur ^ 1;
    if (s + 1 < 32) {
#pragma unroll
      for (int i = 0; i < 4; ++i)
        a[nxt][i] = *(const bf16x8*)(baseA + (size_t)((ri0 + i) * 32 + s + 1) * 512);
#pragma unroll
      for (int j = 0; j < 4; ++j)
        b[nxt][j] = *(const bf16x8*)(baseB + (size_t)((nj0 + j) * 32 + s + 1) * 512);
    }
#pragma unroll
    for (int i = 0; i < 4; ++i)
#pragma unroll
      for (int j = 0; j < 4; ++j)
        acc[i][j] = __builtin_amdgcn_mfma_f32_16x16x32_bf16(a[cur][i], b[cur][j],
                                                            acc[i][j], 0, 0, 0);
  }

  int   rowv[4][4];
  float wrow[4][4];
#pragma unroll
  for (int i = 0; i < 4; ++i)
#pragma unroll
    for (int r = 0; r < 4; ++r) {
      int gr = m0 + wm * 64 + i * 16 + fq * 4 + r;
      bool valid = gr < cnt;
      rowv[i][r] = valid ? pair_token[e * MAXP + gr] : -1;
      wrow[i][r] = valid ? pair_w[e * MAXP + gr] : 0.f;
    }
  if (use_part) {
#pragma unroll
    for (int j = 0; j < 4; ++j) {
      int col = n0 + wn * 64 + j * 16 + fm;
      float bev = be[e * DIM + col];
#pragma unroll
      for (int i = 0; i < 4; ++i)
#pragma unroll
        for (int r = 0; r < 4; ++r) {
          int v = rowv[i][r];
          if (v >= 0)
            part[(size_t)v * DIM + col] = wrow[i][r] * (acc[i][j][r] + bev);
        }
    }
  } else {
#pragma unroll
    for (int j = 0; j < 4; ++j) {
      int col = n0 + wn * 64 + j * 16 + fm;
      float bev = be[e * DIM + col];
#pragma unroll
      for (int i = 0; i < 4; ++i)
#pragma unroll
        for (int r = 0; r < 4; ++r) {
          int v = rowv[i][r];
          if (v >= 0)
            atomicAdd(Y + (size_t)(v >> 1) * DIM + col,
                      wrow[i][r] * (acc[i][j][r] + bev));
        }
    }
  }
}

// ---------------------------------------------------------------------------
// Y[t][d] = part[2t][d] + part[2t+1][d]; 2048 blocks, 4 float4 per thread.
// ---------------------------------------------------------------------------
__global__ __launch_bounds__(256) void reduce_pairs(
    const float* __restrict__ part, float* __restrict__ Y) {
  const int g0 = blockIdx.x * 256 + threadIdx.x;
#pragma unroll
  for (int it = 0; it < 4; ++it) {
    const int g = g0 + it * (2048 * 256);
    const int t = g >> 8;
    const int o = (g & 255) * 4;
    const f32x4 a = *(const f32x4*)(part + (size_t)(2 * t) * DIM + o);
    const f32x4 b = *(const f32x4*)(part + (size_t)(2 * t + 1) * DIM + o);
    *(f32x4*)(Y + (size_t)t * DIM + o) = a + b;
  }
}

// ---------------------------------------------------------------------------
extern "C" void kernel_launch(void* const* d_in, const int* in_sizes, int n_in,
                              void* d_out, int out_size, void* d_ws, size_t ws_size,
                              hipStream_t stream) {
  const float* x  = (const float*)d_in[0];
  const float* Wg = (const float*)d_in[1];
  const float* bg = (const float*)d_in[2];
  const float* We = (const float*)d_in[3];
  const float* be = (const float*)d_in[4];
  float* Y = (float*)d_out;

  const size_t MB = 1024 * 1024;
  char* ws = (char*)d_ws;
  unsigned short* Xbf = (unsigned short*)ws;                 // 16 MiB @ 0
  unsigned short* Wf  = (unsigned short*)(ws + 16 * MB);     // 16 MiB @ 16
  unsigned short* Af  = (unsigned short*)(ws + 32 * MB);     // 36 MiB @ 32 (<=136 tiles)
  const size_t part_bytes = (size_t)NTOK * 2 * DIM * 4;      // 64 MiB
  const size_t need_full = 68 * MB + part_bytes + 1 * MB;    // 133 MiB
  const int use_part = ws_size >= need_full;
  float* part = (float*)(ws + 68 * MB);
  char* p2 = ws + 68 * MB + (use_part ? part_bytes : 0);
  int*    counts     = (int*)p2;                             // 16 ints (+tile_base)
  int*    pair_token = (int*)(p2 + 256);
  float*  pair_w     = (float*)(p2 + 256 + 262144);
  int*    tok_ee     = (int*)(p2 + 256 + 2 * 262144);
  float2* tok_w      = (float2*)(p2 + 256 + 2 * 262144 + 32768);

  if (!use_part)
    hipMemsetAsync(d_out, 0, (size_t)out_size * sizeof(float), stream);

  prep_kernel<<<4096, 256, 0, stream>>>(We, Wf, x, Wg, bg, Xbf, tok_ee, tok_w);
  compact_kernel<<<1, 1024, 0, stream>>>(tok_ee, tok_w, counts, pair_token,
                                         pair_w);
  regather<<<NEXP * 2 * (MAXP / BM), 256, 0, stream>>>(Xbf, counts, pair_token, Af);
  moe_gemm<<<8 * 8 * (NTOK / BM), 256, 0, stream>>>(
      Af, Wf, be, counts, pair_token, pair_w, part, Y, use_part);
  if (use_part)
    reduce_pairs<<<2048, 256, 0, stream>>>(part, Y);
}

// Round 8
// 237.930 us; speedup vs baseline: 1.3329x; 1.3329x over previous
//
#include <hip/hip_runtime.h>
#include <stdint.h>

#define NTOK   8192
#define DIM    1024
#define NEXP   8
#define MAXP   8192

#define BM 128
#define BN 128
#define BK 32

typedef float  f32x4  __attribute__((ext_vector_type(4)));
typedef __bf16 bf16x8 __attribute__((ext_vector_type(8)));

typedef __attribute__((address_space(1))) const void* gas_ptr;
typedef __attribute__((address_space(3))) void*       las_ptr;

__device__ __forceinline__ unsigned short f32_to_bf16(float f) {
  union { float f; unsigned int u; } v; v.f = f;
  unsigned int u = v.u;
  unsigned int r = (u + 0x7FFFu + ((u >> 16) & 1u)) >> 16;
  return (unsigned short)r;
}

// ---------------------------------------------------------------------------
// Fused prep.
// Blocks [0,2048): We[e][d][h] fp32 -> Wt[e][h][d] bf16 (B^T, contiguous k).
// Blocks [2048,2560): gate scores, 4 TOKENS PER WAVE (Wg reuse x4), fp64
// accumulate + butterfly; also x->bf16.
// ---------------------------------------------------------------------------
__global__ __launch_bounds__(256) void prep_kernel(
    const float* __restrict__ We, unsigned short* __restrict__ Wt,
    const float* __restrict__ x, const float* __restrict__ Wg,
    const float* __restrict__ bg, unsigned short* __restrict__ Xbf,
    int* __restrict__ tok_ee, float2* __restrict__ tok_w) {
  __shared__ float tile[64][65];
  const int bid = blockIdx.x;
  if (bid < 2048) {
    const int e  = bid >> 8;
    const int d0 = ((bid >> 4) & 15) * 64;
    const int h0 = (bid & 15) * 64;
    const int t  = threadIdx.x;
    const int tx = t & 63, ty = t >> 6;
    const float* src = We + (size_t)e * DIM * DIM;
#pragma unroll
    for (int i = 0; i < 16; ++i) {
      int d = ty + i * 4;
      tile[d][tx] = src[(size_t)(d0 + d) * DIM + (h0 + tx)];
    }
    __syncthreads();
    unsigned short* dst = Wt + (size_t)e * DIM * DIM;
    const int tx2 = t & 31, ty8 = t >> 5;
#pragma unroll
    for (int i = 0; i < 8; ++i) {
      int h = ty8 + i * 8;
      int d = tx2 * 2;
      unsigned int pk = (unsigned int)f32_to_bf16(tile[d][h]) |
                        ((unsigned int)f32_to_bf16(tile[d + 1][h]) << 16);
      *(unsigned int*)&dst[(size_t)(h0 + h) * DIM + d0 + d] = pk;
    }
    return;
  }
  // ---- gate scores: 4 tokens per wave ----
  const int blk  = bid - 2048;                 // 0..511
  const int wave = threadIdx.x >> 6;
  const int lane = threadIdx.x & 63;
  const int tok0 = blk * 16 + wave * 4;

  float xs[4][16];
#pragma unroll
  for (int t = 0; t < 4; ++t) {
    const float* xr = x + (size_t)(tok0 + t) * DIM + lane * 16;
#pragma unroll
    for (int i = 0; i < 4; ++i)
      *(f32x4*)&xs[t][i * 4] = *(const f32x4*)(xr + i * 4);
  }
#pragma unroll
  for (int t = 0; t < 4; ++t) {
    unsigned int pk[8];
#pragma unroll
    for (int i = 0; i < 8; ++i)
      pk[i] = (unsigned int)f32_to_bf16(xs[t][2 * i]) |
              ((unsigned int)f32_to_bf16(xs[t][2 * i + 1]) << 16);
    uint4* xb = (uint4*)(Xbf + (size_t)(tok0 + t) * DIM + lane * 16);
    xb[0] = make_uint4(pk[0], pk[1], pk[2], pk[3]);
    xb[1] = make_uint4(pk[4], pk[5], pk[6], pk[7]);
  }

  double acc[4][8];
#pragma unroll
  for (int t = 0; t < 4; ++t)
#pragma unroll
    for (int e = 0; e < 8; ++e) acc[t][e] = 0.0;

  const float* wr = Wg + (size_t)(lane * 16) * NEXP;
#pragma unroll
  for (int i = 0; i < 16; ++i) {
    f32x4 wa = *(const f32x4*)(wr + i * 8);
    f32x4 wb = *(const f32x4*)(wr + i * 8 + 4);
    double w0 = wa[0], w1 = wa[1], w2 = wa[2], w3 = wa[3];
    double w4 = wb[0], w5 = wb[1], w6 = wb[2], w7 = wb[3];
#pragma unroll
    for (int t = 0; t < 4; ++t) {
      double xd = (double)xs[t][i];
      acc[t][0] += xd * w0; acc[t][1] += xd * w1;
      acc[t][2] += xd * w2; acc[t][3] += xd * w3;
      acc[t][4] += xd * w4; acc[t][5] += xd * w5;
      acc[t][6] += xd * w6; acc[t][7] += xd * w7;
    }
  }
#pragma unroll
  for (int m = 1; m < 64; m <<= 1)
#pragma unroll
    for (int t = 0; t < 4; ++t)
#pragma unroll
      for (int e = 0; e < 8; ++e) acc[t][e] += __shfl_xor(acc[t][e], m, 64);

  if (lane == 0) {
#pragma unroll
    for (int t = 0; t < 4; ++t) {
      float s[8];
#pragma unroll
      for (int e = 0; e < 8; ++e) s[e] = (float)acc[t][e] + bg[e];
      int i0 = 0; float v0 = s[0];
#pragma unroll
      for (int e = 1; e < 8; ++e) if (s[e] > v0) { v0 = s[e]; i0 = e; }
      int i1 = -1; float v1 = -3.4e38f;
#pragma unroll
      for (int e = 0; e < 8; ++e) if (e != i0 && s[e] > v1) { v1 = s[e]; i1 = e; }
      float t1 = expf(v1 - v0);
      float den = 1.0f + t1;
      tok_ee[tok0 + t] = i0 | (i1 << 8);
      tok_w[tok0 + t]  = make_float2(1.0f / den, t1 / den);
    }
  }
}

// ---------------------------------------------------------------------------
// Deterministic compaction. pair_token[slot] = (tok<<1)|which.
// ---------------------------------------------------------------------------
__global__ __launch_bounds__(1024) void compact_kernel(
    const int* __restrict__ tok_ee, const float2* __restrict__ tok_w,
    int* __restrict__ counts, int* __restrict__ pair_token,
    float* __restrict__ pair_w) {
  __shared__ int wave_cnt[16][NEXP];
  __shared__ int wave_off[16][NEXP];
  __shared__ int base[NEXP];
  __shared__ int chunk_tot[NEXP];
  const int tid = threadIdx.x, wave = tid >> 6, lane = tid & 63;
  if (tid < NEXP) base[tid] = 0;
  __syncthreads();
  for (int c = 0; c < NTOK / 1024; ++c) {
    const int t = c * 1024 + tid;
    const int p = tok_ee[t];
    const int e0 = p & 255, e1 = (p >> 8) & 255;
    const float2 w = tok_w[t];
    int pre0 = 0, pre1 = 0;
    const unsigned long long below = (1ull << lane) - 1ull;
#pragma unroll
    for (int e = 0; e < NEXP; ++e) {
      unsigned long long m = __ballot(e0 == e || e1 == e);
      if (e0 == e) pre0 = __popcll(m & below);
      if (e1 == e) pre1 = __popcll(m & below);
      if (lane == 0) wave_cnt[wave][e] = __popcll(m);
    }
    __syncthreads();
    if (tid < NEXP) {
      int s = 0;
      for (int w2 = 0; w2 < 16; ++w2) {
        wave_off[w2][tid] = s;
        s += wave_cnt[w2][tid];
      }
      chunk_tot[tid] = s;
    }
    __syncthreads();
    const int s0 = base[e0] + wave_off[wave][e0] + pre0;
    const int s1 = base[e1] + wave_off[wave][e1] + pre1;
    pair_token[e0 * MAXP + s0] = (t << 1);     pair_w[e0 * MAXP + s0] = w.x;
    pair_token[e1 * MAXP + s1] = (t << 1) | 1; pair_w[e1 * MAXP + s1] = w.y;
    __syncthreads();
    if (tid < NEXP) base[tid] += chunk_tot[tid];
    __syncthreads();
  }
  if (tid < NEXP) counts[tid] = base[tid];
}

// ---------------------------------------------------------------------------
// Grouped GEMM — R5 structure (best measured): double-buffered LDS via
// global_load_lds, one barrier per K-iter, expert->XCD swizzle (e = id&7).
// Epilogue: plain stores into part[(tok*2+which)*DIM+col] (use_part), else
// atomicAdd into Y.
// ---------------------------------------------------------------------------
__global__ __launch_bounds__(256) void moe_gemm(
    const unsigned short* __restrict__ Xbf, const unsigned short* __restrict__ Wt,
    const float* __restrict__ be, const int* __restrict__ counts,
    const int* __restrict__ pair_token, const float* __restrict__ pair_w,
    float* __restrict__ part, float* __restrict__ Y, int use_part) {
  const int id  = blockIdx.x;
  const int e   = id & 7;
  const int n0  = ((id >> 3) & 7) * BN;
  const int m0  = (id >> 6) * BM;
  const int cnt = counts[e];
  if (m0 >= cnt) return;

  __shared__ __align__(16) unsigned short As[2][BM * BK];
  __shared__ __align__(16) unsigned short Bs[2][BN * BK];

  const int tid  = threadIdx.x;
  const int wave = tid >> 6;
  const int lane = tid & 63;
  const int fm   = lane & 15;
  const int fq   = lane >> 4;
  const int wm   = wave >> 1;
  const int wn   = wave & 1;

  const int srow = wave * 32 + (lane >> 2);
  const int kc   = (lane & 3) * 8;
  const unsigned short* gA[2];
  const unsigned short* gB[2];
#pragma unroll
  for (int c = 0; c < 2; ++c) {
    int r  = srow + c * 16;
    int gr = m0 + r;
    int tk = (gr < cnt) ? (pair_token[e * MAXP + gr] >> 1) : 0;
    gA[c] = Xbf + (size_t)tk * DIM + kc;
    gB[c] = Wt + (size_t)e * DIM * DIM + (size_t)(n0 + r) * DIM + kc;
  }

#define STAGE(buf, koff)                                                      \
  {                                                                           \
    _Pragma("unroll") for (int c = 0; c < 2; ++c) {                           \
      __builtin_amdgcn_global_load_lds(                                       \
          (gas_ptr)(uintptr_t)(gA[c] + (koff)),                               \
          (las_ptr)(uintptr_t)(&As[buf][(wave * 2 + c) * 512]), 16, 0, 0);    \
      __builtin_amdgcn_global_load_lds(                                       \
          (gas_ptr)(uintptr_t)(gB[c] + (koff)),                               \
          (las_ptr)(uintptr_t)(&Bs[buf][(wave * 2 + c) * 512]), 16, 0, 0);    \
    }                                                                         \
  }

  f32x4 acc[4][4];
#pragma unroll
  for (int i = 0; i < 4; ++i)
#pragma unroll
    for (int j = 0; j < 4; ++j) { f32x4 z = {0.f, 0.f, 0.f, 0.f}; acc[i][j] = z; }

  STAGE(0, 0);
  int cur = 0;
  for (int k0 = 0; k0 < DIM; k0 += BK) {
    __syncthreads();
    if (k0 + BK < DIM) STAGE(cur ^ 1, k0 + BK);

    bf16x8 af[4], bfr[4];
#pragma unroll
    for (int i = 0; i < 4; ++i)
      af[i] = *(const bf16x8*)&As[cur][(wm * 64 + i * 16 + fm) * BK + fq * 8];
#pragma unroll
    for (int j = 0; j < 4; ++j)
      bfr[j] = *(const bf16x8*)&Bs[cur][(wn * 64 + j * 16 + fm) * BK + fq * 8];
#pragma unroll
    for (int i = 0; i < 4; ++i)
#pragma unroll
      for (int j = 0; j < 4; ++j)
        acc[i][j] = __builtin_amdgcn_mfma_f32_16x16x32_bf16(af[i], bfr[j],
                                                            acc[i][j], 0, 0, 0);
    cur ^= 1;
  }
#undef STAGE

  int   rowv[4][4];
  float wrow[4][4];
#pragma unroll
  for (int i = 0; i < 4; ++i)
#pragma unroll
    for (int r = 0; r < 4; ++r) {
      int gr = m0 + wm * 64 + i * 16 + fq * 4 + r;
      bool valid = gr < cnt;
      rowv[i][r] = valid ? pair_token[e * MAXP + gr] : -1;
      wrow[i][r] = valid ? pair_w[e * MAXP + gr] : 0.f;
    }
  if (use_part) {
#pragma unroll
    for (int j = 0; j < 4; ++j) {
      int col = n0 + wn * 64 + j * 16 + fm;
      float bev = be[e * DIM + col];
#pragma unroll
      for (int i = 0; i < 4; ++i)
#pragma unroll
        for (int r = 0; r < 4; ++r) {
          int v = rowv[i][r];
          if (v >= 0)
            part[(size_t)v * DIM + col] = wrow[i][r] * (acc[i][j][r] + bev);
        }
    }
  } else {
#pragma unroll
    for (int j = 0; j < 4; ++j) {
      int col = n0 + wn * 64 + j * 16 + fm;
      float bev = be[e * DIM + col];
#pragma unroll
      for (int i = 0; i < 4; ++i)
#pragma unroll
        for (int r = 0; r < 4; ++r) {
          int v = rowv[i][r];
          if (v >= 0)
            atomicAdd(Y + (size_t)(v >> 1) * DIM + col,
                      wrow[i][r] * (acc[i][j][r] + bev));
        }
    }
  }
}

// ---------------------------------------------------------------------------
// Y[t][d] = part[2t][d] + part[2t+1][d]; 2048 blocks, 4 float4 per thread.
// ---------------------------------------------------------------------------
__global__ __launch_bounds__(256) void reduce_pairs(
    const float* __restrict__ part, float* __restrict__ Y) {
  const int g0 = blockIdx.x * 256 + threadIdx.x;
#pragma unroll
  for (int it = 0; it < 4; ++it) {
    const int g = g0 + it * (2048 * 256);
    const int t = g >> 8;
    const int o = (g & 255) * 4;
    const f32x4 a = *(const f32x4*)(part + (size_t)(2 * t) * DIM + o);
    const f32x4 b = *(const f32x4*)(part + (size_t)(2 * t + 1) * DIM + o);
    *(f32x4*)(Y + (size_t)t * DIM + o) = a + b;
  }
}

// ---------------------------------------------------------------------------
extern "C" void kernel_launch(void* const* d_in, const int* in_sizes, int n_in,
                              void* d_out, int out_size, void* d_ws, size_t ws_size,
                              hipStream_t stream) {
  const float* x  = (const float*)d_in[0];
  const float* Wg = (const float*)d_in[1];
  const float* bg = (const float*)d_in[2];
  const float* We = (const float*)d_in[3];
  const float* be = (const float*)d_in[4];
  float* Y = (float*)d_out;

  const size_t MB = 1024 * 1024;
  char* ws = (char*)d_ws;
  unsigned short* Xbf = (unsigned short*)ws;                 // 16 MiB
  unsigned short* Wt  = (unsigned short*)(ws + 16 * MB);     // 16 MiB
  const size_t part_bytes = (size_t)NTOK * 2 * DIM * 4;      // 64 MiB
  const size_t need = 32 * MB + part_bytes + 1 * MB;
  const int use_part = ws_size >= need;
  float* part = (float*)(ws + 32 * MB);
  char* p2 = ws + 32 * MB + (use_part ? part_bytes : 0);
  int*    counts     = (int*)p2;
  int*    pair_token = (int*)(p2 + 256);
  float*  pair_w     = (float*)(p2 + 256 + 262144);
  int*    tok_ee     = (int*)(p2 + 256 + 2 * 262144);
  float2* tok_w      = (float2*)(p2 + 256 + 2 * 262144 + 32768);

  if (!use_part)
    hipMemsetAsync(d_out, 0, (size_t)out_size * sizeof(float), stream);

  prep_kernel<<<2560, 256, 0, stream>>>(We, Wt, x, Wg, bg, Xbf, tok_ee, tok_w);
  compact_kernel<<<1, 1024, 0, stream>>>(tok_ee, tok_w, counts, pair_token,
                                         pair_w);
  moe_gemm<<<8 * 8 * (NTOK / BM), 256, 0, stream>>>(
      Xbf, Wt, be, counts, pair_token, pair_w, part, Y, use_part);
  if (use_part)
    reduce_pairs<<<2048, 256, 0, stream>>>(part, Y);
}

// Round 10
// 228.346 us; speedup vs baseline: 1.3888x; 1.0420x over previous
//
#include <hip/hip_runtime.h>
#include <stdint.h>

#define NTOK   8192
#define DIM    1024
#define NEXP   8
#define MAXP   8192

#define BM 128
#define BN 128
#define BK 32

typedef float    f32x4  __attribute__((ext_vector_type(4)));
typedef __bf16   bf16x8 __attribute__((ext_vector_type(8)));
typedef _Float16 h16x8  __attribute__((ext_vector_type(8)));

typedef __attribute__((address_space(1))) const void* gas_ptr;
typedef __attribute__((address_space(3))) void*       las_ptr;

__device__ __forceinline__ unsigned short f32_to_bf16(float f) {
  union { float f; unsigned int u; } v; v.f = f;
  unsigned int u = v.u;
  unsigned int r = (u + 0x7FFFu + ((u >> 16) & 1u)) >> 16;
  return (unsigned short)r;
}

// ---------------------------------------------------------------------------
// Fused prep.
// Blocks [0,2048): We[e][d][h] fp32 -> Wf bf16 TILE-LINEAR:
//   block (e,nt,kt) = 4096 elems (128 n-rows x 32 k), element offset
//   ((e*8+nt)*32 + kt)*4096 + n_local*32 + k_local.   [stride <<12 — R9 fix]
//   This is exactly the LDS image the GEMM stages: B staging reads are 1KB
//   contiguous per wave-instruction; prep writes are 1KB/wave coalesced.
// Blocks [2048,2560): gate scores, 4 tokens/wave, fp64; also x->bf16.
// ---------------------------------------------------------------------------
__global__ __launch_bounds__(256) void prep_kernel(
    const float* __restrict__ We, unsigned short* __restrict__ Wf,
    const float* __restrict__ x, const float* __restrict__ Wg,
    const float* __restrict__ bg, unsigned short* __restrict__ Xbf,
    int* __restrict__ tok_ee, float2* __restrict__ tok_w) {
  __shared__ float tile[64][65];
  const int bid = blockIdx.x;
  if (bid < 2048) {
    const int e  = bid >> 8;
    const int d0 = ((bid >> 4) & 15) * 64;   // k block (covers kt = d0/32, +1)
    const int h0 = (bid & 15) * 64;          // n block
    const int t  = threadIdx.x;
    const int tx = t & 63, ty = t >> 6;
    const float* src = We + (size_t)e * DIM * DIM;
#pragma unroll
    for (int i = 0; i < 16; ++i) {
      int d = ty + i * 4;
      tile[d][tx] = src[(size_t)(d0 + d) * DIM + (h0 + tx)];
    }
    __syncthreads();
    const int nt    = h0 >> 7;
    const int rbase = h0 & 64;               // 0 or 64 within the 128-row tile
    const int hl    = t >> 2;                // 0..63 local n
    const int k8    = t & 3;                 // which 8-k group
#pragma unroll
    for (int reg = 0; reg < 2; ++reg) {
      const int kt = (d0 >> 5) + reg;
      unsigned int pk[4];
#pragma unroll
      for (int q = 0; q < 4; ++q) {
        int dl = reg * 32 + k8 * 8 + q * 2;
        pk[q] = (unsigned int)f32_to_bf16(tile[dl][hl]) |
                ((unsigned int)f32_to_bf16(tile[dl + 1][hl]) << 16);
      }
      size_t base = (((size_t)(e * 8 + nt) * 32 + kt) << 12) +   // 4096/block
                    (size_t)(rbase + hl) * 32 + k8 * 8;
      *(uint4*)&Wf[base] = make_uint4(pk[0], pk[1], pk[2], pk[3]);
    }
    return;
  }
  // ---- gate scores: 4 tokens per wave ----
  const int blk  = bid - 2048;
  const int wave = threadIdx.x >> 6;
  const int lane = threadIdx.x & 63;
  const int tok0 = blk * 16 + wave * 4;

  float xs[4][16];
#pragma unroll
  for (int t = 0; t < 4; ++t) {
    const float* xr = x + (size_t)(tok0 + t) * DIM + lane * 16;
#pragma unroll
    for (int i = 0; i < 4; ++i)
      *(f32x4*)&xs[t][i * 4] = *(const f32x4*)(xr + i * 4);
  }
#pragma unroll
  for (int t = 0; t < 4; ++t) {
    unsigned int pk[8];
#pragma unroll
    for (int i = 0; i < 8; ++i)
      pk[i] = (unsigned int)f32_to_bf16(xs[t][2 * i]) |
              ((unsigned int)f32_to_bf16(xs[t][2 * i + 1]) << 16);
    uint4* xb = (uint4*)(Xbf + (size_t)(tok0 + t) * DIM + lane * 16);
    xb[0] = make_uint4(pk[0], pk[1], pk[2], pk[3]);
    xb[1] = make_uint4(pk[4], pk[5], pk[6], pk[7]);
  }

  double acc[4][8];
#pragma unroll
  for (int t = 0; t < 4; ++t)
#pragma unroll
    for (int e = 0; e < 8; ++e) acc[t][e] = 0.0;

  const float* wr = Wg + (size_t)(lane * 16) * NEXP;
#pragma unroll
  for (int i = 0; i < 16; ++i) {
    f32x4 wa = *(const f32x4*)(wr + i * 8);
    f32x4 wb = *(const f32x4*)(wr + i * 8 + 4);
    double w0 = wa[0], w1 = wa[1], w2 = wa[2], w3 = wa[3];
    double w4 = wb[0], w5 = wb[1], w6 = wb[2], w7 = wb[3];
#pragma unroll
    for (int t = 0; t < 4; ++t) {
      double xd = (double)xs[t][i];
      acc[t][0] += xd * w0; acc[t][1] += xd * w1;
      acc[t][2] += xd * w2; acc[t][3] += xd * w3;
      acc[t][4] += xd * w4; acc[t][5] += xd * w5;
      acc[t][6] += xd * w6; acc[t][7] += xd * w7;
    }
  }
#pragma unroll
  for (int m = 1; m < 64; m <<= 1)
#pragma unroll
    for (int t = 0; t < 4; ++t)
#pragma unroll
      for (int e = 0; e < 8; ++e) acc[t][e] += __shfl_xor(acc[t][e], m, 64);

  if (lane == 0) {
#pragma unroll
    for (int t = 0; t < 4; ++t) {
      float s[8];
#pragma unroll
      for (int e = 0; e < 8; ++e) s[e] = (float)acc[t][e] + bg[e];
      int i0 = 0; float v0 = s[0];
#pragma unroll
      for (int e = 1; e < 8; ++e) if (s[e] > v0) { v0 = s[e]; i0 = e; }
      int i1 = -1; float v1 = -3.4e38f;
#pragma unroll
      for (int e = 0; e < 8; ++e) if (e != i0 && s[e] > v1) { v1 = s[e]; i1 = e; }
      float t1 = expf(v1 - v0);
      float den = 1.0f + t1;
      tok_ee[tok0 + t] = i0 | (i1 << 8);
      tok_w[tok0 + t]  = make_float2(1.0f / den, t1 / den);
    }
  }
}

// ---------------------------------------------------------------------------
// Parallel deterministic compaction: one block per expert (8 blocks), one
// ballot per chunk; slots in ascending token order. pair_token = (tok<<1)|w.
// ---------------------------------------------------------------------------
__global__ __launch_bounds__(1024) void compact_kernel(
    const int* __restrict__ tok_ee, const float2* __restrict__ tok_w,
    int* __restrict__ counts, int* __restrict__ pair_token,
    float* __restrict__ pair_w) {
  __shared__ int wave_cnt[16];
  __shared__ int wave_off[16];
  const int e = blockIdx.x;
  const int tid = threadIdx.x, wave = tid >> 6, lane = tid & 63;
  int base = 0;                               // live in thread 0 only
  for (int c = 0; c < NTOK / 1024; ++c) {
    const int t = c * 1024 + tid;
    const int p = tok_ee[t];
    const bool m0 = ((p & 255) == e);
    const bool m1 = (((p >> 8) & 255) == e);
    const unsigned long long m = __ballot(m0 || m1);
    const int pre = __popcll(m & ((1ull << lane) - 1ull));
    if (lane == 0) wave_cnt[wave] = __popcll(m);
    __syncthreads();
    if (tid == 0) {
      int s = base;
      for (int w = 0; w < 16; ++w) { wave_off[w] = s; s += wave_cnt[w]; }
      base = s;
    }
    __syncthreads();
    if (m0 || m1) {
      const float2 w = tok_w[t];
      const int slot = wave_off[wave] + pre;
      pair_token[e * MAXP + slot] = (t << 1) | (m1 ? 1 : 0);
      pair_w[e * MAXP + slot]     = m1 ? w.y : w.x;
    }
    __syncthreads();                          // protect wave_cnt/off reuse
  }
  if (tid == 0) counts[e] = base;
}

// ---------------------------------------------------------------------------
// Grouped GEMM — dbuf-LDS + tile-linear B (contiguous 1KB staging reads).
// Expert->XCD swizzle (e = id&7). Epilogue: fp16 partials (use_part), else
// atomicAdd fp32 into Y.
// ---------------------------------------------------------------------------
__global__ __launch_bounds__(256) void moe_gemm(
    const unsigned short* __restrict__ Xbf, const unsigned short* __restrict__ Wf,
    const float* __restrict__ be, const int* __restrict__ counts,
    const int* __restrict__ pair_token, const float* __restrict__ pair_w,
    _Float16* __restrict__ part, float* __restrict__ Y, int use_part) {
  const int id  = blockIdx.x;
  const int e   = id & 7;
  const int nt  = (id >> 3) & 7;
  const int n0  = nt * BN;
  const int m0  = (id >> 6) * BM;
  const int cnt = counts[e];
  if (m0 >= cnt) return;

  __shared__ __align__(16) unsigned short As[2][BM * BK];
  __shared__ __align__(16) unsigned short Bs[2][BN * BK];

  const int tid  = threadIdx.x;
  const int wave = tid >> 6;
  const int lane = tid & 63;
  const int fm   = lane & 15;
  const int fq   = lane >> 4;
  const int wm   = wave >> 1;
  const int wn   = wave & 1;

  const int srow = wave * 32 + (lane >> 2);
  const int kc   = (lane & 3) * 8;
  const unsigned short* gA[2];
#pragma unroll
  for (int c = 0; c < 2; ++c) {
    int r  = srow + c * 16;
    int gr = m0 + r;
    int tk = (gr < cnt) ? (pair_token[e * MAXP + gr] >> 1) : 0;
    gA[c] = Xbf + (size_t)tk * DIM + kc;
  }
  // tile-linear B: for k-step k0 (kt = k0/32), (wave,c) source =
  //   Wf + ((e*8+nt)*32 + kt)*4096 + (wave*2+c)*512 + lane*8
  //      = gB + k0*128 + c*512        [kt*4096 == k0*128]
  const unsigned short* gB = Wf + (((size_t)(e * 8 + nt) * 32) << 12) +
                             (wave * 2) * 512 + lane * 8;

#define STAGE(buf, k0v)                                                       \
  {                                                                           \
    _Pragma("unroll") for (int c = 0; c < 2; ++c) {                           \
      __builtin_amdgcn_global_load_lds(                                       \
          (gas_ptr)(uintptr_t)(gA[c] + (k0v)),                                \
          (las_ptr)(uintptr_t)(&As[buf][(wave * 2 + c) * 512]), 16, 0, 0);    \
      __builtin_amdgcn_global_load_lds(                                       \
          (gas_ptr)(uintptr_t)(gB + (size_t)(k0v) * 128 + c * 512),           \
          (las_ptr)(uintptr_t)(&Bs[buf][(wave * 2 + c) * 512]), 16, 0, 0);    \
    }                                                                         \
  }

  f32x4 acc[4][4];
#pragma unroll
  for (int i = 0; i < 4; ++i)
#pragma unroll
    for (int j = 0; j < 4; ++j) { f32x4 z = {0.f, 0.f, 0.f, 0.f}; acc[i][j] = z; }

  STAGE(0, 0);
  int cur = 0;
  for (int k0 = 0; k0 < DIM; k0 += BK) {
    __syncthreads();
    if (k0 + BK < DIM) STAGE(cur ^ 1, k0 + BK);

    bf16x8 af[4], bfr[4];
#pragma unroll
    for (int i = 0; i < 4; ++i)
      af[i] = *(const bf16x8*)&As[cur][(wm * 64 + i * 16 + fm) * BK + fq * 8];
#pragma unroll
    for (int j = 0; j < 4; ++j)
      bfr[j] = *(const bf16x8*)&Bs[cur][(wn * 64 + j * 16 + fm) * BK + fq * 8];
#pragma unroll
    for (int i = 0; i < 4; ++i)
#pragma unroll
      for (int j = 0; j < 4; ++j)
        acc[i][j] = __builtin_amdgcn_mfma_f32_16x16x32_bf16(af[i], bfr[j],
                                                            acc[i][j], 0, 0, 0);
    cur ^= 1;
  }
#undef STAGE

  int   rowv[4][4];
  float wrow[4][4];
#pragma unroll
  for (int i = 0; i < 4; ++i)
#pragma unroll
    for (int r = 0; r < 4; ++r) {
      int gr = m0 + wm * 64 + i * 16 + fq * 4 + r;
      bool valid = gr < cnt;
      rowv[i][r] = valid ? pair_token[e * MAXP + gr] : -1;
      wrow[i][r] = valid ? pair_w[e * MAXP + gr] : 0.f;
    }
  if (use_part) {
#pragma unroll
    for (int j = 0; j < 4; ++j) {
      int col = n0 + wn * 64 + j * 16 + fm;
      float bev = be[e * DIM + col];
#pragma unroll
      for (int i = 0; i < 4; ++i)
#pragma unroll
        for (int r = 0; r < 4; ++r) {
          int v = rowv[i][r];
          if (v >= 0)
            part[(size_t)v * DIM + col] =
                (_Float16)(wrow[i][r] * (acc[i][j][r] + bev));
        }
    }
  } else {
#pragma unroll
    for (int j = 0; j < 4; ++j) {
      int col = n0 + wn * 64 + j * 16 + fm;
      float bev = be[e * DIM + col];
#pragma unroll
      for (int i = 0; i < 4; ++i)
#pragma unroll
        for (int r = 0; r < 4; ++r) {
          int v = rowv[i][r];
          if (v >= 0)
            atomicAdd(Y + (size_t)(v >> 1) * DIM + col,
                      wrow[i][r] * (acc[i][j][r] + bev));
        }
    }
  }
}

// ---------------------------------------------------------------------------
// Y[t][d] = part[2t][d] + part[2t+1][d]; fp16 in, fp32 out. 8 elems/thread.
// ---------------------------------------------------------------------------
__global__ __launch_bounds__(256) void reduce_pairs(
    const _Float16* __restrict__ part, float* __restrict__ Y) {
  const int g = blockIdx.x * 256 + threadIdx.x;   // 8-elem group index
  const int t = g >> 7;                           // 128 groups per token
  const int o = (g & 127) * 8;
  const h16x8 a = *(const h16x8*)(part + (size_t)(2 * t) * DIM + o);
  const h16x8 b = *(const h16x8*)(part + (size_t)(2 * t + 1) * DIM + o);
  float* y = Y + (size_t)t * DIM + o;
  f32x4 lo = {(float)a[0] + (float)b[0], (float)a[1] + (float)b[1],
              (float)a[2] + (float)b[2], (float)a[3] + (float)b[3]};
  f32x4 hi = {(float)a[4] + (float)b[4], (float)a[5] + (float)b[5],
              (float)a[6] + (float)b[6], (float)a[7] + (float)b[7]};
  *(f32x4*)y = lo;
  *(f32x4*)(y + 4) = hi;
}

// ---------------------------------------------------------------------------
extern "C" void kernel_launch(void* const* d_in, const int* in_sizes, int n_in,
                              void* d_out, int out_size, void* d_ws, size_t ws_size,
                              hipStream_t stream) {
  const float* x  = (const float*)d_in[0];
  const float* Wg = (const float*)d_in[1];
  const float* bg = (const float*)d_in[2];
  const float* We = (const float*)d_in[3];
  const float* be = (const float*)d_in[4];
  float* Y = (float*)d_out;

  const size_t MB = 1024 * 1024;
  char* ws = (char*)d_ws;
  unsigned short* Xbf = (unsigned short*)ws;                 // 16 MiB
  unsigned short* Wf  = (unsigned short*)(ws + 16 * MB);     // 16 MiB
  const size_t part_bytes = (size_t)NTOK * 2 * DIM * 2;      // 32 MiB (fp16)
  const size_t need = 32 * MB + part_bytes + 1 * MB;
  const int use_part = ws_size >= need;
  _Float16* part = (_Float16*)(ws + 32 * MB);
  char* p2 = ws + 32 * MB + (use_part ? part_bytes : 0);
  int*    counts     = (int*)p2;
  int*    pair_token = (int*)(p2 + 256);
  float*  pair_w     = (float*)(p2 + 256 + 262144);
  int*    tok_ee     = (int*)(p2 + 256 + 2 * 262144);
  float2* tok_w      = (float2*)(p2 + 256 + 2 * 262144 + 32768);

  if (!use_part)
    hipMemsetAsync(d_out, 0, (size_t)out_size * sizeof(float), stream);

  prep_kernel<<<2560, 256, 0, stream>>>(We, Wf, x, Wg, bg, Xbf, tok_ee, tok_w);
  compact_kernel<<<NEXP, 1024, 0, stream>>>(tok_ee, tok_w, counts, pair_token,
                                            pair_w);
  moe_gemm<<<8 * 8 * (NTOK / BM), 256, 0, stream>>>(
      Xbf, Wf, be, counts, pair_token, pair_w, part, Y, use_part);
  if (use_part)
    reduce_pairs<<<NTOK * DIM / 8 / 256, 256, 0, stream>>>(part, Y);
}